// Round 4
// baseline (298.353 us; speedup 1.0000x reference)
//
#include <hip/hip_runtime.h>
#include <math.h>

#define BB 8
#define CC 256
#define CQ 32
#define NN 2304   // 48*48
#define NT 36     // NN/64
#define NJ 36

typedef __attribute__((ext_vector_type(8))) short bf16x8;
typedef __attribute__((ext_vector_type(4))) float f32x4;
typedef __attribute__((ext_vector_type(4))) unsigned short u16x4;
typedef unsigned short ushort_t;
typedef unsigned int u32;

#define LOG2E 1.44269504088896f

static __device__ inline unsigned short f2bf(float f) {
    unsigned u = __builtin_bit_cast(unsigned, f);
    return (unsigned short)((u + 0x7fffu + ((u >> 16) & 1u)) >> 16);
}

// workspace layout (ushort units):
//  qx @ 0, kx @ S8, qy @ 2*S8, ky @ 3*S8   (each B*N*32, pixel-major bf16)
//  vx @ 4*S8, vy @ 4*S8+SV                 (each B*C*N, channel-major bf16, PLAIN)
//  Wall @ 4*S8+2*SV : [2][320][256] bf16   (rows 0-31 Wq*log2e, 32-63 Wk, 64-319 Wv)
//  ball @ +163840   : [2][320] float biases
#define S8  ((size_t)BB * NN * CQ)
#define SV  ((size_t)BB * NN * CC)
#define WOFF (4 * S8 + 2 * SV)

// ---------------------------------------------------------------------------
// Weight convert: fp32 -> bf16, fold log2(e) into Wq/bq.
// ---------------------------------------------------------------------------
__global__ __launch_bounds__(256) void wcvt_kernel(
    const float* __restrict__ wqx, const float* __restrict__ bqx,
    const float* __restrict__ wkx, const float* __restrict__ bkx,
    const float* __restrict__ wvx, const float* __restrict__ bvx,
    const float* __restrict__ wqy, const float* __restrict__ bqy,
    const float* __restrict__ wky, const float* __restrict__ bky,
    const float* __restrict__ wvy, const float* __restrict__ bvy,
    ushort_t* __restrict__ ws)
{
    ushort_t* Wall = ws + WOFF;
    float*    ball = (float*)(ws + WOFF + 2 * 320 * 256);

    int id = blockIdx.x * 256 + threadIdx.x;   // 0..40959
    int row = id >> 6;                          // 0..639
    int c4  = (id & 63) * 4;
    int br  = row >= 320;
    int r   = row - br * 320;

    const float* src;
    float scale = 1.0f;
    if (r < 32)      { src = (br ? wqy : wqx) + (size_t)r * CC;        scale = LOG2E; }
    else if (r < 64) { src = (br ? wky : wkx) + (size_t)(r - 32) * CC; }
    else             { src = (br ? wvy : wvx) + (size_t)(r - 64) * CC; }

    float4 v = *(const float4*)(src + c4);
    u16x4 pk;
    pk[0] = f2bf(v.x * scale); pk[1] = f2bf(v.y * scale);
    pk[2] = f2bf(v.z * scale); pk[3] = f2bf(v.w * scale);
    *(u16x4*)(Wall + (size_t)row * CC + c4) = pk;

    if (id < 640) {
        int row2 = id, br2 = row2 >= 320, r2 = row2 - br2 * 320;
        const float* bsrc; float sc2 = 1.0f;
        if (r2 < 32)      { bsrc = (br2 ? bqy : bqx) + r2;        sc2 = LOG2E; }
        else if (r2 < 64) { bsrc = (br2 ? bky : bkx) + (r2 - 32); }
        else              { bsrc = (br2 ? bvy : bvx) + (r2 - 64); }
        ball[row2] = bsrc[0] * sc2;
    }
}

// ---------------------------------------------------------------------------
// Projection via MFMA, LDS-staged A-transpose.
// Block = (b, br, 64-px tile); stage x-tile [64px][256c] bf16 in LDS with
// coalesced float4 global loads, then 20 output tiles x 8 K-chunk MFMAs.
// ---------------------------------------------------------------------------
#define XST 264   // x-tile row stride (elems): 528B = 132dw = 4-bank offset/row

__global__ __launch_bounds__(256, 2) void proj_kernel(
    const float* __restrict__ x, const float* __restrict__ y,
    ushort_t* __restrict__ ws)
{
    __shared__ __align__(16) ushort_t Xs[64 * XST];    // 33 KB
    __shared__ __align__(16) ushort_t vls[256 * 64];   // 32 KB

    const int t = threadIdx.x, w = t >> 6, lane = t & 63;
    const int l15 = lane & 15, quad = lane >> 4;

    const int id   = blockIdx.x;        // 0..575
    const int b    = id & 7;
    const int rest = id >> 3;           // 0..71
    const int br   = rest >= NT;
    const int tile = br ? rest - NT : rest;

    const float* src = br ? y : x;
    const ushort_t* Wall = ws + WOFF + (size_t)br * 320 * CC;
    const float*    ball = (float*)(ws + WOFF + 2 * 320 * 256) + br * 320;

    ushort_t* qbuf = ws + (size_t)br * 2 * S8;
    ushort_t* kbuf = qbuf + S8;
    ushort_t* vbufg = ws + 4 * S8 + (size_t)br * SV;

    // ---- stage x-tile: coalesced float4 loads, bf16 transpose into LDS ----
#pragma unroll
    for (int rep = 0; rep < 16; rep++) {
        int e  = rep * 256 + t;          // 0..4095
        int c  = e >> 4;                 // 0..255
        int p4 = e & 15;                 // px-group of 4
        float4 v = *(const float4*)&src[((size_t)b * CC + c) * NN + tile * 64 + p4 * 4];
        Xs[(p4 * 4 + 0) * XST + c] = f2bf(v.x);
        Xs[(p4 * 4 + 1) * XST + c] = f2bf(v.y);
        Xs[(p4 * 4 + 2) * XST + c] = f2bf(v.z);
        Xs[(p4 * 4 + 3) * XST + c] = f2bf(v.w);
    }
    __syncthreads();

    // ---- A fragments from LDS ----
    bf16x8 af[8];
#pragma unroll
    for (int q = 0; q < 8; q++)
        af[q] = *(const bf16x8*)&Xs[(w * 16 + l15) * XST + q * 32 + quad * 8];

    // ---- 20 output tiles x 8 K-chunk MFMAs (W from global, L2-hot) ----
    const ushort_t* wb = Wall + (size_t)l15 * CC + quad * 8;
    f32x4 acc[20];
#pragma unroll
    for (int ot = 0; ot < 20; ot++) {
        f32x4 a = (f32x4){0.f, 0.f, 0.f, 0.f};
#pragma unroll
        for (int q = 0; q < 8; q++)
            a = __builtin_amdgcn_mfma_f32_16x16x32_bf16(
                    af[q], *(const bf16x8*)(wb + (size_t)(ot * 16) * CC + q * 32),
                    a, 0, 0, 0);
        acc[ot] = a;
    }

    // ---- epilogue: q/k direct, v via LDS transpose (chunk-XOR swizzled) ----
#pragma unroll
    for (int ot = 0; ot < 4; ot++) {
        int o = ot * 16 + l15;          // 0..63
        float bias = ball[o];
        ushort_t* dst = (o < 32 ? qbuf : kbuf);
        int oc = o & 31;
#pragma unroll
        for (int r = 0; r < 4; r++) {
            int pxl = w * 16 + quad * 4 + r;
            dst[((size_t)b * NN + tile * 64 + pxl) * CQ + oc] = f2bf(acc[ot][r] + bias);
        }
    }
#pragma unroll
    for (int ot = 4; ot < 20; ot++) {
        int o_loc = (ot - 4) * 16 + l15;   // 0..255
        float bias = ball[64 + o_loc];
#pragma unroll
        for (int r = 0; r < 4; r++) {
            int pxl = w * 16 + quad * 4 + r;
            vls[o_loc * 64 + (((pxl >> 3) ^ (o_loc & 7)) * 8) + (pxl & 7)] =
                f2bf(acc[ot][r] + bias);
        }
    }
    __syncthreads();
#pragma unroll
    for (int rep = 0; rep < 8; rep++) {
        int cid = rep * 256 + t;           // 0..2047
        int o_loc = cid >> 3, pc = cid & 7;
        *(uint4*)(vbufg + ((size_t)b * CC + o_loc) * NN + tile * 64 + pc * 8) =
            *(uint4*)&vls[o_loc * 64 + ((pc ^ (o_loc & 7)) * 8)];
    }
}

// ---------------------------------------------------------------------------
// Flash attention v3: no-max softmax (p = 2^s), V direct global->registers
// (wave-private channels), LDS = double-buffered Ps only, ONE barrier/iter.
// ---------------------------------------------------------------------------
#define TI 64
#define TJ 64
#define TJP 72

__global__ __launch_bounds__(256, 3) void flash_kernel(
    const float* __restrict__ x, const float* __restrict__ y,
    const float* __restrict__ gxp, const float* __restrict__ gyp,
    const ushort_t* __restrict__ ws, float* __restrict__ out)
{
    __shared__ __align__(16) unsigned char smem[20480];  // Ps[2][64][72] (18.4KB) | Ob (20.5KB)
    ushort_t* PsBase = (ushort_t*)smem;
    float*    Ob     = (float*)smem;
    __shared__ __align__(16) float Lrow[TI];

    const int t = threadIdx.x, w = t >> 6, lane = t & 63;
    const int l15 = lane & 15, quad = lane >> 4;

    const int id   = blockIdx.x;        // 0..575
    const int b    = id & 7;            // XCD-affine batch
    const int rest = id >> 3;
    const int br   = rest >= NT;
    const int it   = br ? rest - NT : rest;
    const int i0   = it * TI;

    const ushort_t* Qb = ws + (br ? 0 : 2 * S8);   // br0: qy/ky, br1: qx/kx
    const ushort_t* Kb = Qb + S8;
    const ushort_t* Vb = ws + 4 * S8 + (br ? SV : 0);
    const float* res = br ? y : x;
    const float gamma = br ? gyp[0] : gxp[0];
    float* op = out + (size_t)br * SV + (size_t)b * CC * NN;

    // Q fragment, held all kernel: rows i0 + 16w + l15, k = quad*8..+8
    bf16x8 qf = *(const bf16x8*)(Qb + ((size_t)b * NN + i0 + w * 16 + l15) * CQ + quad * 8);

    f32x4 acc[4][4];
#pragma unroll
    for (int i = 0; i < 4; i++)
#pragma unroll
        for (int j = 0; j < 4; j++) acc[i][j] = (f32x4){0.f, 0.f, 0.f, 0.f};
    float l_loc[4] = {0.f, 0.f, 0.f, 0.f};

    // per-lane global bases
    const ushort_t* kp = Kb + ((size_t)b * NN + l15) * CQ + quad * 8;
    // V: wave-private channels w*64..w*64+64; frag (ct,ks): c = w*64+ct*16+l15,
    // px = jb + ks*32 + quad*8
    const ushort_t* vp = Vb + ((size_t)b * CC + w * 64 + l15) * NN + quad * 8;

    // prologue: kf(0)
    bf16x8 kf[4];
#pragma unroll
    for (int n = 0; n < 4; n++)
        kf[n] = *(const bf16x8*)(kp + (size_t)(n * 16) * CQ);

    for (int jt = 0; jt < NJ; jt++) {
        const int jb = jt * TJ;
        ushort_t* Ps = PsBase + (jt & 1) * (TI * TJP);

        // issue V(jt) loads first (drained by this iter's barrier)
        bf16x8 vf[4][2];
#pragma unroll
        for (int ct = 0; ct < 4; ct++)
#pragma unroll
            for (int ks = 0; ks < 2; ks++)
                vf[ct][ks] = *(const bf16x8*)(vp + (size_t)(ct * 16) * NN + jb + ks * 32);

        // S = Q K^T (registers only)
        f32x4 s[4];
#pragma unroll
        for (int n = 0; n < 4; n++)
            s[n] = __builtin_amdgcn_mfma_f32_16x16x32_bf16(qf, kf[n],
                       (f32x4){0.f, 0.f, 0.f, 0.f}, 0, 0, 0);

        // p = 2^s, per-lane row-sum accumulate, pack to Ps[cur]
#pragma unroll
        for (int n = 0; n < 4; n++)
#pragma unroll
            for (int r = 0; r < 4; r++) {
                float p = __builtin_amdgcn_exp2f(s[n][r]);
                l_loc[r] += p;
                Ps[(w * 16 + quad * 4 + r) * TJP + n * 16 + l15] = f2bf(p);
            }

        __syncthreads();   // publishes Ps[cur]; implies PV(jt-1) done -> Ps[cur^1]
                           // free next iter; vmcnt(0) drain completes vf loads

        // prefetch K(jt+1)
        if (jt + 1 < NJ) {
            const ushort_t* kn = kp + (size_t)((jt + 1) * TJ) * CQ;
#pragma unroll
            for (int n = 0; n < 4; n++)
                kf[n] = *(const bf16x8*)(kn + (size_t)(n * 16) * CQ);
        }

        // PV: 32 MFMAs, A-frags from Ps[cur], B-frags = vf (registers)
#pragma unroll
        for (int ks = 0; ks < 2; ks++) {
            bf16x8 pf[4];
#pragma unroll
            for (int rt = 0; rt < 4; rt++)
                pf[rt] = *(const bf16x8*)&Ps[(rt * 16 + l15) * TJP + ks * 32 + quad * 8];
#pragma unroll
            for (int rt = 0; rt < 4; rt++)
#pragma unroll
                for (int ct = 0; ct < 4; ct++)
                    acc[rt][ct] = __builtin_amdgcn_mfma_f32_16x16x32_bf16(
                        pf[rt], vf[ct][ks], acc[rt][ct], 0, 0, 0);
        }
    }

    // final row-sum reduction across l15
#pragma unroll
    for (int r = 0; r < 4; r++) {
        float l = l_loc[r];
        l += __shfl_xor(l, 1);
        l += __shfl_xor(l, 2);
        l += __shfl_xor(l, 4);
        l += __shfl_xor(l, 8);
        l_loc[r] = l;
    }
    if (l15 == 0) {
        f32x4 lv = {l_loc[0], l_loc[1], l_loc[2], l_loc[3]};
        *(f32x4*)&Lrow[w * 16 + quad * 4] = lv;
    }
    __syncthreads();

    // epilogue: normalize, gamma, residual, coalesced [C][N] store
    for (int rt = 0; rt < 4; rt++) {
        f32x4 lv = *(f32x4*)&Lrow[rt * 16 + quad * 4];
        f32x4 gi;
#pragma unroll
        for (int r = 0; r < 4; r++) gi[r] = gamma / lv[r];
        __syncthreads();   // Ob region (aliases Ps) free
#pragma unroll
        for (int ct = 0; ct < 4; ct++) {
            int c = w * 64 + ct * 16 + l15;
            f32x4 ov;
#pragma unroll
            for (int r = 0; r < 4; r++) ov[r] = acc[rt][ct][r] * gi[r];
            *(f32x4*)&Ob[c * 20 + quad * 4] = ov;
        }
        __syncthreads();
#pragma unroll
        for (int rep = 0; rep < 4; rep++) {
            int c  = rep * 64 + (t >> 2);
            int p4 = t & 3;
            f32x4 v = *(f32x4*)&Ob[c * 20 + p4 * 4];
            size_t go = ((size_t)b * CC + c) * NN + i0 + rt * 16 + p4 * 4;
            f32x4 r4 = *(const f32x4*)&res[go];
            v += r4;
            *(f32x4*)&op[(size_t)c * NN + i0 + rt * 16 + p4 * 4] = v;
        }
    }
}

extern "C" void kernel_launch(void* const* d_in, const int* in_sizes, int n_in,
                              void* d_out, int out_size, void* d_ws, size_t ws_size,
                              hipStream_t stream)
{
    const float* x   = (const float*)d_in[0];
    const float* y   = (const float*)d_in[1];
    const float* wqx = (const float*)d_in[2];
    const float* bqx = (const float*)d_in[3];
    const float* wkx = (const float*)d_in[4];
    const float* bkx = (const float*)d_in[5];
    const float* wvx = (const float*)d_in[6];
    const float* bvx = (const float*)d_in[7];
    const float* wqy = (const float*)d_in[8];
    const float* bqy = (const float*)d_in[9];
    const float* wky = (const float*)d_in[10];
    const float* bky = (const float*)d_in[11];
    const float* wvy = (const float*)d_in[12];
    const float* bvy = (const float*)d_in[13];
    const float* gx  = (const float*)d_in[14];
    const float* gy  = (const float*)d_in[15];
    ushort_t* ws = (ushort_t*)d_ws;
    float* out = (float*)d_out;

    wcvt_kernel<<<dim3(160), 256, 0, stream>>>(wqx, bqx, wkx, bkx, wvx, bvx,
                                               wqy, bqy, wky, bky, wvy, bvy, ws);
    proj_kernel<<<dim3(576), 256, 0, stream>>>(x, y, ws);
    flash_kernel<<<dim3(576), 256, 0, stream>>>(x, y, gx, gy, ws, out);
}